// Round 7
// baseline (7127.542 us; speedup 1.0000x reference)
//
#include <hip/hip_runtime.h>
#include <cstddef>

#define Bn 32
#define Sn 512
#define Hn 512
#define Rn (Bn*Sn)
#define NLAYER 4
constexpr size_t NHe = (size_t)Rn * Hn;   // 8,388,608 elements per (B,S,H) tensor

typedef __attribute__((ext_vector_type(8))) _Float16 f16x8;
typedef __attribute__((ext_vector_type(4))) float f32x4;

__device__ __forceinline__ float sigf(float x) { return 1.f / (1.f + __expf(-x)); }
// 16B global -> LDS DMA (lane-linear dest; LDS base is wave-uniform + lane*16)
__device__ __forceinline__ void gl_lds16(const void* g, void* l) {
  __builtin_amdgcn_global_load_lds((const __attribute__((address_space(1))) void*)g,
                                   (__attribute__((address_space(3))) void*)l, 16, 0, 0);
}

// fp16 A-frag slot for M=32 operands (dh/comb): element (b,k) ->
// (((kcT*2+rg)*4+quad)*16+l15)*8 + j  with rg=b>>4,l15=b&15,kcT=k>>5,quad=(k>>3)&3,j=k&7
__device__ __forceinline__ int a32slot(int b, int k) {
  int kcT = k >> 5, quad = (k >> 3) & 3, j = k & 7, rg = b >> 4, l15 = b & 15;
  return ((((kcT * 2 + rg) * 4 + quad) * 16 + l15) * 8) + j;
}

// ---------------- init: h = init_h*m, c = init_c*m ----------------
__global__ void k_init(const float* __restrict__ ih, const float* __restrict__ ic,
                       const int* __restrict__ mask,
                       float* __restrict__ h, float* __restrict__ c) {
  size_t i = (size_t)blockIdx.x * blockDim.x + threadIdx.x;  // over NHe/4
  size_t n = i >> 7;
  float m = (float)mask[n];
  float4 b = ((const float4*)ih)[i];
  float4 d = ((const float4*)ic)[i];
  b.x *= m; b.y *= m; b.z *= m; b.w *= m;
  d.x *= m; d.y *= m; d.z *= m; d.w *= m;
  ((float4*)h)[i] = b; ((float4*)c)[i] = d;
}

// ---------------- mean2 (once): dh16 (frag fp16), dc ----------------
__global__ void k_mean2(const float* __restrict__ x, const float* __restrict__ y,
                        _Float16* __restrict__ dh16, float* __restrict__ oy) {
  int idx = blockIdx.x * blockDim.x + threadIdx.x;
  int b = idx >> 9, k = idx & 511;
  const float* px = x + (size_t)b * Sn * Hn + k;
  const float* py = y + (size_t)b * Sn * Hn + k;
  float sx = 0.f, sy = 0.f;
#pragma unroll 8
  for (int t = 0; t < Sn; ++t) { sx += px[(size_t)t * Hn]; sy += py[(size_t)t * Hn]; }
  oy[idx] = sy * (1.f / Sn);
  dh16[a32slot(b, k)] = (_Float16)(sx * (1.f / Sn));
}

// ---------------- mean over s: two-stage, float4 ----------------
__global__ void k_mean1a(const float* __restrict__ x, float* __restrict__ part) {
  int b = blockIdx.x, sc = blockIdx.y;          // 32 x 8
  int k4 = threadIdx.x & 127;                   // float4 over 512 k
  int so = threadIdx.x >> 7;                    // 0/1
  const float4* px = (const float4*)x + ((size_t)(b * Sn + sc * 64 + so)) * 128 + k4;
  float4 s = make_float4(0.f, 0.f, 0.f, 0.f);
#pragma unroll 4
  for (int t = 0; t < 32; ++t) {
    float4 v = px[(size_t)t * 256];
    s.x += v.x; s.y += v.y; s.z += v.z; s.w += v.w;
  }
  ((float4*)part)[((size_t)(sc * 2 + so) * Bn + b) * 128 + k4] = s;
}
__global__ void k_mean1b(const float* __restrict__ part, _Float16* __restrict__ comb16) {
  int idx = blockIdx.x * blockDim.x + threadIdx.x;   // B*H/4 = 4096
  int b = idx >> 7, k4 = idx & 127;
  float4 s = make_float4(0.f, 0.f, 0.f, 0.f);
#pragma unroll
  for (int p = 0; p < 16; ++p) {
    float4 v = ((const float4*)part)[((size_t)p * Bn + b) * 128 + k4];
    s.x += v.x; s.y += v.y; s.z += v.z; s.w += v.w;
  }
  float vv[4] = {s.x, s.y, s.z, s.w};
#pragma unroll
  for (int jj = 0; jj < 4; ++jj)
    comb16[a32slot(b, k4 * 4 + jj)] = (_Float16)(vv[jj] * (1.f / Sn));
}

// ---------------- small-GEMM weight pre-swizzle (once): gW0..4 + Wd0..7 ----------------
__global__ void k_convS(const float* __restrict__ gW, const float* __restrict__ Wd,
                        _Float16* __restrict__ Shat) {
  int kcT = blockIdx.x, nT4 = blockIdx.y, mat = blockIdx.z;  // 16,4,13
  int tid = threadIdx.x;  // 256
  const float* w = (mat < 5) ? (gW + (size_t)mat * 262144)
                             : (Wd + (size_t)(mat - 5) * 262144);
  size_t sb = ((size_t)((mat * 4 + nT4) * 16 + kcT)) * 4096;
#pragma unroll
  for (int half = 0; half < 2; ++half) {
    int st = half * 256 + tid;             // slot 0..511
    int nj = st >> 6, quad = (st >> 4) & 3, l15 = st & 15;
    int n = nT4 * 128 + nj * 16 + l15;
    int k0 = kcT * 32 + quad * 8;
    f16x8 w8;
#pragma unroll
    for (int j = 0; j < 8; ++j) w8[j] = (_Float16)w[(size_t)(k0 + j) * Hn + n];
    *(f16x8*)&Shat[sb + (size_t)st * 8] = w8;
  }
}

// ---------------- k_small: 13 batched M=32 GEMMs via MFMA (LDS-free) ----------------
__global__ __launch_bounds__(256) void k_small(const _Float16* __restrict__ dh16,
                                               const _Float16* __restrict__ comb16,
                                               const _Float16* __restrict__ Shat,
                                               float* __restrict__ S) {
  const int mat = blockIdx.x, nT4 = blockIdx.y;  // 13, 4
  const int tid = threadIdx.x;
  const int lane = tid & 63, wid = tid >> 6;
  const int quad = lane >> 4, l15 = lane & 15;
  const _Float16* A16 = (mat == 1 || mat == 3) ? comb16 : dh16;
  const _Float16* Sb = Shat + ((size_t)((mat * 4 + nT4) * 16)) * 4096;

  f32x4 acc[2][2];
#pragma unroll
  for (int rg = 0; rg < 2; ++rg)
#pragma unroll
    for (int nj = 0; nj < 2; ++nj) acc[rg][nj] = (f32x4){0.f, 0.f, 0.f, 0.f};

#pragma unroll 4
  for (int kcT = 0; kcT < 16; ++kcT) {
    f16x8 a0 = *(const f16x8*)&A16[(((kcT * 2 + 0) * 4 + quad) * 16 + l15) * 8];
    f16x8 a1 = *(const f16x8*)&A16[(((kcT * 2 + 1) * 4 + quad) * 16 + l15) * 8];
    f16x8 b0 = *(const f16x8*)&Sb[(size_t)kcT * 4096 + (((wid * 2 + 0) * 4 + quad) * 16 + l15) * 8];
    f16x8 b1 = *(const f16x8*)&Sb[(size_t)kcT * 4096 + (((wid * 2 + 1) * 4 + quad) * 16 + l15) * 8];
    acc[0][0] = __builtin_amdgcn_mfma_f32_16x16x32_f16(a0, b0, acc[0][0], 0, 0, 0);
    acc[0][1] = __builtin_amdgcn_mfma_f32_16x16x32_f16(a0, b1, acc[0][1], 0, 0, 0);
    acc[1][0] = __builtin_amdgcn_mfma_f32_16x16x32_f16(a1, b0, acc[1][0], 0, 0, 0);
    acc[1][1] = __builtin_amdgcn_mfma_f32_16x16x32_f16(a1, b1, acc[1][1], 0, 0, 0);
  }
#pragma unroll
  for (int rg = 0; rg < 2; ++rg)
#pragma unroll
    for (int nj = 0; nj < 2; ++nj)
#pragma unroll
      for (int r = 0; r < 4; ++r) {
        int brow = rg * 16 + quad * 4 + r;
        int col = nT4 * 128 + (wid * 2 + nj) * 16 + l15;
        S[(size_t)mat * 16384 + brow * 512 + col] = acc[rg][nj][r];
      }
}

// ---------------- gates combine: gd, go, gfA from S ----------------
__global__ void k_gates2(const float* __restrict__ S, const float* __restrict__ gb,
                         float* __restrict__ gd, float* __restrict__ go,
                         float* __restrict__ gfA) {
  int idx = blockIdx.x * blockDim.x + threadIdx.x;  // B*H = 16384
  int k = idx & 511;
  gd[idx] = sigf(S[idx] + S[16384 + idx] + gb[k]);
  go[idx] = sigf(S[2 * 16384 + idx] + S[3 * 16384 + idx] + gb[512 + k]);
  gfA[idx] = S[4 * 16384 + idx] + gb[1024 + k];
}

// ---------------- dummy combine: reads gemm1d partials ----------------
__global__ void k_dummy2(const float* __restrict__ pnum, const float* __restrict__ pden,
                         const float* __restrict__ gd, const float* __restrict__ go,
                         const float* __restrict__ dc,
                         _Float16* __restrict__ dh16o, float* __restrict__ dc2) {
  int idx = blockIdx.x * blockDim.x + threadIdx.x;  // B*H
  int b = idx >> 9, k = idx & 511;
  float ed = __expf(gd[idx]);
  float num = ed * dc[idx], den = ed;
#pragma unroll
  for (int q = 0; q < 4; ++q) {
    num += pnum[(size_t)(b * 4 + q) * 512 + k];
    den += pden[(size_t)(b * 4 + q) * 512 + k];
  }
  float d = num / den;
  dc2[idx] = d;
  dh16o[a32slot(b, k)] = (_Float16)(go[idx] * tanhf(d));
}

// ---------------- weight pre-swizzle: f32 [g][k][n] -> fp16 frag-order superblocks ----------------
// Bhat superblock sb = (t*16 + nT)*16 + kcT, 8192 halfs (16KB) each.
__global__ void k_convw(const float* __restrict__ Wx, const float* __restrict__ Wh,
                        const float* __restrict__ Wsm, const float* __restrict__ Wi,
                        _Float16* __restrict__ Bhat) {
  int kcT = blockIdx.x, nT = blockIdx.y, tg = blockIdx.z;  // 16,16,40
  int t = tg >> 3, g = tg & 7;
  const float* base;
  if (t == 0)      base = Wx  + (size_t)g * 262144;
  else if (t == 1) base = Wh  + (size_t)g * 524288;
  else if (t == 2) base = Wh  + (size_t)g * 524288 + 262144;
  else if (t == 3) base = Wsm + (size_t)g * 262144;
  else             base = Wi  + (size_t)g * 262144;
  size_t sbase = ((size_t)(t * 16 + nT) * 16 + kcT) * 8192 + (size_t)g * 1024;
  int lane = threadIdx.x;  // 64 threads
  for (int cch = lane; cch < 128; cch += 64) {
    int ni = cch >> 6, quad = (cch >> 4) & 3, l15 = cch & 15;
    int n = nT * 32 + ni * 16 + l15;
    int k0 = kcT * 32 + quad * 8;
    f16x8 w8;
#pragma unroll
    for (int j = 0; j < 8; ++j) w8[j] = (_Float16)base[(size_t)(k0 + j) * Hn + n];
    *(f16x8*)&Bhat[sbase + (size_t)cch * 8] = w8;
  }
}

// ---------------- gWhf pre-swizzle (once): superblock (nT4*16+kcT), 4096 halfs ----------------
__global__ void k_convG(const float* __restrict__ gW, _Float16* __restrict__ Ghat) {
  int kcT = blockIdx.x, nT4 = blockIdx.y;  // 16, 4
  int tid = threadIdx.x;                   // 256
  const float* w = gW + (size_t)5 * Hn * Hn;
  size_t sb = ((size_t)(nT4 * 16 + kcT)) * 4096;
#pragma unroll
  for (int half = 0; half < 2; ++half) {
    int st = half * 256 + tid;             // slot 0..511
    int nj = st >> 6, quad = (st >> 4) & 3, l15 = st & 15;
    int n = nT4 * 128 + nj * 16 + l15;
    int k0 = kcT * 32 + quad * 8;
    f16x8 w8;
#pragma unroll
    for (int j = 0; j < 8; ++j) w8[j] = (_Float16)w[(size_t)(k0 + j) * Hn + n];
    *(f16x8*)&Ghat[sb + (size_t)st * 8] = w8;
  }
}

// ---------------- A pre-convert per layer: ALL terms 0..3 in one pass ----------------
__global__ void k_prepAll(const float* __restrict__ h, const int* __restrict__ pos,
                          _Float16* __restrict__ Ahat) {
  const int mb = blockIdx.x, kcT = blockIdx.y;  // 128,16
  const int tid = threadIdx.x;  // 256
#pragma unroll
  for (int half = 0; half < 2; ++half) {
    int st = half * 256 + tid;
    int rg = st >> 6, quad = (st >> 4) & 3, l15 = st & 15;
    int r = mb * 128 + rg * 16 + l15;
    int srow = r & (Sn - 1);
    int k0 = kcT * 32 + quad * 8;
    const float* base = h + (size_t)r * Hn + k0;
    float v0[8], v1[8], v2[8], v3[8];
#pragma unroll
    for (int j = 0; j < 8; ++j) { v0[j] = base[j]; v1[j] = 0.f; v2[j] = 0.f; v3[j] = 0.f; }
    if (srow >= 1) { const float* p = base - Hn;
#pragma unroll
      for (int j = 0; j < 8; ++j) v1[j] += p[j]; }
    if (srow >= 2) { const float* p = base - 2 * Hn;
#pragma unroll
      for (int j = 0; j < 8; ++j) v1[j] += p[j]; }
    if (srow <= Sn - 2) { const float* p = base + Hn;
#pragma unroll
      for (int j = 0; j < 8; ++j) v2[j] += p[j]; }
    if (srow <= Sn - 3) { const float* p = base + 2 * Hn;
#pragma unroll
      for (int j = 0; j < 8; ++j) v2[j] += p[j]; }
    int pp = pos[r];
    if (pp) {
      const float* p = h + ((size_t)((r >> 9) * Sn + pp - 1)) * Hn + k0;
#pragma unroll
      for (int j = 0; j < 8; ++j) v3[j] = p[j];
    }
    size_t stoff = (size_t)st * 8;
    f16x8 o0, o1, o2, o3;
#pragma unroll
    for (int j = 0; j < 8; ++j) {
      o0[j] = (_Float16)v0[j]; o1[j] = (_Float16)v1[j];
      o2[j] = (_Float16)v2[j]; o3[j] = (_Float16)v3[j];
    }
    *(f16x8*)&Ahat[((size_t)(0 * 128 + mb) * 16 + kcT) * 4096 + stoff] = o0;
    *(f16x8*)&Ahat[((size_t)(1 * 128 + mb) * 16 + kcT) * 4096 + stoff] = o1;
    *(f16x8*)&Ahat[((size_t)(2 * 128 + mb) * 16 + kcT) * 4096 + stoff] = o2;
    *(f16x8*)&Ahat[((size_t)(3 * 128 + mb) * 16 + kcT) * 4096 + stoff] = o3;
  }
}

// word term (t=4): layer-invariant, run once
__global__ void k_prepW(const float* __restrict__ w, const int* __restrict__ mask,
                        _Float16* __restrict__ Ahat) {
  const int mb = blockIdx.x, kcT = blockIdx.y;  // 128,16
  const int tid = threadIdx.x;
  size_t sb = ((size_t)(4 * 128 + mb) * 16 + kcT) * 4096;
#pragma unroll
  for (int half = 0; half < 2; ++half) {
    int st = half * 256 + tid;
    int rg = st >> 6, quad = (st >> 4) & 3, l15 = st & 15;
    int r = mb * 128 + rg * 16 + l15;
    int k0 = kcT * 32 + quad * 8;
    float mf = (float)mask[r];
    const float* base = w + (size_t)r * Hn + k0;
    f16x8 o8;
#pragma unroll
    for (int j = 0; j < 8; ++j) o8[j] = (_Float16)(base[j] * mf);
    *(f16x8*)&Ahat[sb + (size_t)st * 8] = o8;
  }
}

// ---------------- G-GEMM fused with dummy-softmax partial reduction ----------------
__global__ __launch_bounds__(256, 2) void k_gemm1d(const _Float16* __restrict__ Ahat,
                                                   const _Float16* __restrict__ Ghat,
                                                   const float* __restrict__ gfA,
                                                   const float* __restrict__ cbuf,
                                                   const int* __restrict__ mask,
                                                   float* __restrict__ pnum,
                                                   float* __restrict__ pden) {
  __shared__ _Float16 As[2][4096];
  __shared__ _Float16 Bs[2][4096];
  __shared__ float red[4][2][128];
  const int tid = threadIdx.x;
  const int mb = blockIdx.x, nT4 = blockIdx.y;
  const int lane = tid & 63, wid = tid >> 6;
  const int quad = lane >> 4, l15 = lane & 15;
  const int afo0 = (((wid * 2 + 0) * 4 + quad) * 16 + l15) * 8;
  const int afo1 = (((wid * 2 + 1) * 4 + quad) * 16 + l15) * 8;

  f32x4 acc[2][8];
#pragma unroll
  for (int mi = 0; mi < 2; ++mi)
#pragma unroll
    for (int nj = 0; nj < 8; ++nj) acc[mi][nj] = (f32x4){0.f, 0.f, 0.f, 0.f};

  auto stage = [&](int buf, int kcT) {
    const int4* sa = (const int4*)Ahat + ((size_t)(mb * 16 + kcT) << 9);
    const int4* sbp = (const int4*)Ghat + ((size_t)(nT4 * 16 + kcT) << 9);
#pragma unroll
    for (int q = 0; q < 2; ++q) {
      gl_lds16(sa + q * 256 + tid, &As[buf][(q * 256 + tid) * 8]);
      gl_lds16(sbp + q * 256 + tid, &Bs[buf][(q * 256 + tid) * 8]);
    }
  };

  stage(0, 0);
  __syncthreads();
#pragma unroll 1
  for (int kcT = 0; kcT < 16; ++kcT) {
    const int cur = kcT & 1;
    if (kcT < 15) stage(cur ^ 1, kcT + 1);
    f16x8 a0 = *(const f16x8*)&As[cur][afo0];
    f16x8 a1 = *(const f16x8*)&As[cur][afo1];
#pragma unroll
    for (int nj = 0; nj < 8; ++nj) {
      f16x8 bh = *(const f16x8*)&Bs[cur][((nj * 4 + quad) * 16 + l15) * 8];
      acc[0][nj] = __builtin_amdgcn_mfma_f32_16x16x32_f16(a0, bh, acc[0][nj], 0, 0, 0);
      acc[1][nj] = __builtin_amdgcn_mfma_f32_16x16x32_f16(a1, bh, acc[1][nj], 0, 0, 0);
    }
    __syncthreads();
  }

  // ---- fused dummy-softmax partial epilogue ----
  const int bb = mb >> 2;
  float gfa[8], nsum[8], dsum[8];
#pragma unroll
  for (int nj = 0; nj < 8; ++nj) {
    gfa[nj] = gfA[bb * 512 + nT4 * 128 + nj * 16 + l15];
    nsum[nj] = 0.f; dsum[nj] = 0.f;
  }
#pragma unroll
  for (int mi = 0; mi < 2; ++mi) {
#pragma unroll
    for (int r = 0; r < 4; ++r) {
      int row = mb * 128 + wid * 32 + mi * 16 + quad * 4 + r;
      float mf = (float)mask[row];
      const float* crow = cbuf + (size_t)row * 512 + nT4 * 128 + l15;
#pragma unroll
      for (int nj = 0; nj < 8; ++nj) {
        float e = __expf(sigf(acc[mi][nj][r] + gfa[nj])) * mf;
        nsum[nj] += e * crow[nj * 16];
        dsum[nj] += e;
      }
    }
  }
#pragma unroll
  for (int nj = 0; nj < 8; ++nj) {
    nsum[nj] += __shfl_xor(nsum[nj], 16);
    nsum[nj] += __shfl_xor(nsum[nj], 32);
    dsum[nj] += __shfl_xor(dsum[nj], 16);
    dsum[nj] += __shfl_xor(dsum[nj], 32);
  }
  if (quad == 0) {
#pragma unroll
    for (int nj = 0; nj < 8; ++nj) {
      red[wid][0][nj * 16 + l15] = nsum[nj];
      red[wid][1][nj * 16 + l15] = dsum[nj];
    }
  }
  __syncthreads();
  {
    int cc = tid & 127, which = tid >> 7;   // 256 threads -> 2 x 128
    float v = red[0][which][cc] + red[1][which][cc] + red[2][which][cc] + red[3][which][cc];
    float* dst = which ? pden : pnum;
    dst[(size_t)mb * 512 + nT4 * 128 + cc] = v;
  }
}

// ---------------- mega GEMM: BK=32, 2 buffers, 2 blocks/CU for pipe overlap ----------------
// Tile 256 rows x 32 cols x 8 g, 512 threads = 8 waves (wave = 64r x 16c x 8g).
// 64KB LDS -> 2 blocks/CU: block A's MFMA phase overlaps block B's LDS phase
// (the round-4/6 1-block/CU versions serialized the two pipes in lockstep).
// __syncthreads' implicit vmcnt(0) drain IS the depth-1 prefetch wait; compiler
// auto-inserts partial lgkmcnt between ds_read and MFMA.
__global__ __launch_bounds__(512, 4) void k_mega(
    const float* __restrict__ c,
    const _Float16* __restrict__ Ahat, const _Float16* __restrict__ Bhat,
    const int* __restrict__ pos, const int* __restrict__ mask,
    const float* __restrict__ dc, const float* __restrict__ dWd,
    const float* __restrict__ bias,
    float* __restrict__ hout, float* __restrict__ cout) {
  __shared__ _Float16 As[2][8192];   // 16KB per buffer: [mb2*4096 + slot*8]
  __shared__ _Float16 Bs[2][8192];   // 16KB per buffer: [g*1024 + interior]

  const int tid = threadIdx.x;        // 512
  const int id = blockIdx.x;          // 1024
  const int xcd = id & 7;
  const int loc = id >> 3;            // 0..127
  const int mt = xcd * 8 + (loc >> 4);  // 0..63 (per-XCD contiguous M-tiles)
  const int nT = loc & 15;
  const int m0 = mt * 256;
  const int n0 = nT * 32;
  const int bb = m0 >> 9;             // batch index

  const int lane = tid & 63, wid = tid >> 6;
  const int quad = lane >> 4, l15 = lane & 15;
  const int row_grp = wid >> 1;       // 0..3 -> rows [m0+row_grp*64, +64)
  const int col_half = wid & 1;       // 0..1 -> cols [n0+col_half*16, +16)
  const int mb2 = row_grp >> 1;       // which 128-row A-superblock
  const int rg0 = (row_grp & 1) * 4;  // first 16-row group within superblock

  const int afo = mb2 * 4096 + rg0 * 512 + quad * 128 + l15 * 8;  // + mi*512
  const int bfo = col_half * 512 + quad * 128 + l15 * 8;          // + g*1024

  f32x4 acc[8][4];
#pragma unroll
  for (int g = 0; g < 8; ++g)
#pragma unroll
    for (int mi = 0; mi < 4; ++mi) acc[g][mi] = (f32x4){0.f, 0.f, 0.f, 0.f};

  // 4 loads/thread/step: 2x A superblock (8KB each), 2x B halves (16KB total)
  auto stage = [&](int buf, int cn) {
    const int t = cn >> 4, kcT = cn & 15;
#pragma unroll
    for (int m2 = 0; m2 < 2; ++m2) {
      const int4* src = (const int4*)Ahat +
          ((size_t)((t * 128 + mt * 2 + m2) * 16 + kcT)) * 512;
      gl_lds16(src + tid, &As[buf][m2 * 4096 + tid * 8]);
    }
    const int4* sbp = (const int4*)Bhat + ((size_t)((t * 16 + nT) * 16 + kcT)) * 1024;
    gl_lds16(sbp + tid, &Bs[buf][tid * 8]);
    gl_lds16(sbp + 512 + tid, &Bs[buf][4096 + tid * 8]);
  };

  stage(0, 0);
#pragma unroll 1
  for (int kt = 0; kt < 80; ++kt) {
    const int cur = kt & 1;
    __syncthreads();                 // drains vmcnt(0)+lgkmcnt(0): stage(kt) landed
                                     // everywhere, prior reads retired everywhere
    if (kt < 79) stage(cur ^ 1, kt + 1);   // overwrites buf read at kt-1 (retired)
    const _Float16* Ab = &As[cur][afo];
    const _Float16* Bb = &Bs[cur][bfo];
    f16x8 a0 = *(const f16x8*)&Ab[0];
    f16x8 a1 = *(const f16x8*)&Ab[512];
    f16x8 a2 = *(const f16x8*)&Ab[1024];
    f16x8 a3 = *(const f16x8*)&Ab[1536];
    __builtin_amdgcn_s_setprio(1);
#pragma unroll
    for (int g = 0; g < 8; ++g) {
      f16x8 bg = *(const f16x8*)&Bb[g * 1024];
      acc[g][0] = __builtin_amdgcn_mfma_f32_16x16x32_f16(a0, bg, acc[g][0], 0, 0, 0);
      acc[g][1] = __builtin_amdgcn_mfma_f32_16x16x32_f16(a1, bg, acc[g][1], 0, 0, 0);
      acc[g][2] = __builtin_amdgcn_mfma_f32_16x16x32_f16(a2, bg, acc[g][2], 0, 0, 0);
      acc[g][3] = __builtin_amdgcn_mfma_f32_16x16x32_f16(a3, bg, acc[g][3], 0, 0, 0);
    }
    __builtin_amdgcn_s_setprio(0);
  }

  // ---- fused epilogue (per thread: 16 rows x 1 col) ----
  const int col = n0 + col_half * 16 + l15;
  const float tdcv = dc[bb * Hn + col];
  float biasr[8], dwdr[8];
#pragma unroll
  for (int g = 0; g < 8; ++g) {
    biasr[g] = bias[g * Hn + col];
    dwdr[g] = dWd[((size_t)g * Bn + bb) * Hn + col];
  }

#pragma unroll
  for (int mi = 0; mi < 4; ++mi) {
#pragma unroll
    for (int r = 0; r < 4; ++r) {
      const int row = m0 + row_grp * 64 + mi * 16 + quad * 4 + r;
      const int srow = row & (Sn - 1);
      const float mf = (float)mask[row];
      const int pp = pos[row];
      const size_t rb = (size_t)row * Hn;
      float cf = c[rb + col];
      float cb = 0.f, ca = 0.f;
      if (srow >= 1) cb = c[rb - Hn + col];
      if (srow >= 2) cb += c[rb - 2 * Hn + col];
      if (srow <= Sn - 2) ca = c[rb + Hn + col];
      if (srow <= Sn - 3) ca += c[rb + 2 * Hn + col];
      float sw = pp ? c[((size_t)(bb * Sn + pp - 1)) * Hn + col] : 0.f;
      float z[8];
#pragma unroll
      for (int g = 0; g < 8; ++g)
        z[g] = acc[g][mi][r] + biasr[g] + dwdr[g];
      float e0 = __expf(sigf(z[0]));
      float e1 = __expf(sigf(z[1]));
      float e2 = __expf(sigf(z[2]));
      float e3 = __expf(sigf(z[3]));
      float e4 = __expf(sigf(z[4]));
      float e5 = __expf(sigf(z[5]));
      float inv = 1.f / (e0 + e1 + e2 + e3 + e4 + e5);
      float o = sigf(z[6]);
      float u = tanhf(z[7]);
      float cn = inv * (e0 * cb + e1 * ca + e2 * cf + e3 * tdcv + e4 * sw + e5 * u);
      cout[rb + col] = cn * mf;
      hout[rb + col] = o * tanhf(cn) * mf;
    }
  }
}

extern "C" void kernel_launch(void* const* d_in, const int* in_sizes, int n_in,
                              void* d_out, int out_size, void* d_ws, size_t ws_size,
                              hipStream_t stream) {
  (void)in_sizes; (void)n_in; (void)out_size; (void)ws_size;
  const float* word   = (const float*)d_in[0];
  const float* init_h = (const float*)d_in[1];
  const float* init_c = (const float*)d_in[2];
  const float* Wx     = (const float*)d_in[3];
  const float* Wh     = (const float*)d_in[4];
  const float* Wi     = (const float*)d_in[5];
  const float* Wdm    = (const float*)d_in[6];
  const float* Wsm    = (const float*)d_in[7];
  const float* bias   = (const float*)d_in[8];
  const float* gW     = (const float*)d_in[9];
  const float* gb     = (const float*)d_in[10];
  const int*   pos    = (const int*)d_in[11];
  const int*   mask   = (const int*)d_in[12];

  float* ws = (float*)d_ws;
  size_t off = 0;
  auto alloc = [&](size_t nel) { float* p = ws + off; off += nel; return p; };
  float* cA   = alloc(NHe);
  float* cB   = alloc(NHe);
  float* hS   = alloc(NHe);
  _Float16* Ahat = (_Float16*)alloc(5 * NHe / 2);           // 84 MB
  _Float16* Bhat = (_Float16*)alloc(5 * 8 * 512 * 512 / 2); // 21 MB
  _Float16* Ghat = (_Float16*)alloc(512 * 512 / 2);         // 0.5 MB
  _Float16* Shat = (_Float16*)alloc(13 * 512 * 512 / 2);    // 6.8 MB
  float* S    = alloc(13 * 16384);                          // 0.85 MB
  float* part = alloc(16 * Bn * Hn);
  float* pnum = alloc(128 * 512);
  float* pden = alloc(128 * 512);
  _Float16* dh16A = (_Float16*)alloc(8192);
  _Float16* dh16B = (_Float16*)alloc(8192);
  _Float16* comb16 = (_Float16*)alloc(8192);
  float* dc   = alloc(Bn * Hn);
  float* dc2  = alloc(Bn * Hn);
  float* gd   = alloc(Bn * Hn);
  float* go   = alloc(Bn * Hn);
  float* gfA  = alloc(Bn * Hn);
  // total ~ 217 MB

  dim3 blk(256);
  int g4 = (int)(NHe / 4 / 256);          // 8192 blocks
  int gbh = (Bn * Hn) / 256;              // 64 blocks

  k_convw<<<dim3(16, 16, 40), dim3(64), 0, stream>>>(Wx, Wh, Wsm, Wi, Bhat);
  k_convG<<<dim3(16, 4), blk, 0, stream>>>(gW, Ghat);
  k_convS<<<dim3(16, 4, 13), blk, 0, stream>>>(gW, Wdm, Shat);
  k_prepW<<<dim3(128, 16), blk, 0, stream>>>(word, mask, Ahat);
  k_init<<<g4, blk, 0, stream>>>(init_h, init_c, mask, hS, cA);
  k_mean2<<<gbh, blk, 0, stream>>>(hS, cA, dh16A, dc);

  float* ccur = cA; float* cnxt = cB;
  _Float16* dhc = dh16A; _Float16* dhn = dh16B;
  for (int l = 0; l < NLAYER; ++l) {
    k_prepAll<<<dim3(128, 16), blk, 0, stream>>>(hS, pos, Ahat);
    k_mean1a<<<dim3(Bn, 8), blk, 0, stream>>>(hS, part);
    k_mean1b<<<16, blk, 0, stream>>>(part, comb16);
    k_small<<<dim3(13, 4), blk, 0, stream>>>(dhc, comb16, Shat, S);
    k_gates2<<<gbh, blk, 0, stream>>>(S, gb, gd, go, gfA);
    k_gemm1d<<<dim3(128, 4), blk, 0, stream>>>(Ahat, Ghat, gfA, ccur, mask, pnum, pden);
    k_dummy2<<<gbh, blk, 0, stream>>>(pnum, pden, gd, go, dc, dhn, dc2);

    float* hout = (l == NLAYER - 1) ? (float*)d_out : hS;
    k_mega<<<dim3(1024), dim3(512), 0, stream>>>(
        ccur, Ahat, Bhat, pos, mask, dc, S + (size_t)5 * 16384, bias, hout, cnxt);

    float* t1;
    t1 = ccur; ccur = cnxt; cnxt = t1;
    t1 = dc; dc = dc2; dc2 = t1;
    _Float16* t2 = dhc; dhc = dhn; dhn = t2;
  }
}

// Round 8
// 1837.487 us; speedup vs baseline: 3.8790x; 3.8790x over previous
//
#include <hip/hip_runtime.h>
#include <cstddef>

#define Bn 32
#define Sn 512
#define Hn 512
#define Rn (Bn*Sn)
#define NLAYER 4
constexpr size_t NHe = (size_t)Rn * Hn;   // 8,388,608 elements per (B,S,H) tensor

typedef __attribute__((ext_vector_type(8))) _Float16 f16x8;
typedef __attribute__((ext_vector_type(4))) float f32x4;

__device__ __forceinline__ float sigf(float x) { return 1.f / (1.f + __expf(-x)); }
// 16B global -> LDS DMA (lane-linear dest; LDS base is wave-uniform + lane*16)
__device__ __forceinline__ void gl_lds16(const void* g, void* l) {
  __builtin_amdgcn_global_load_lds((const __attribute__((address_space(1))) void*)g,
                                   (__attribute__((address_space(3))) void*)l, 16, 0, 0);
}
#define VMCNT(n) asm volatile("s_waitcnt vmcnt(" #n ")" ::: "memory")

// fp16 A-frag slot for M=32 operands (dh/comb): element (b,k) ->
// (((kcT*2+rg)*4+quad)*16+l15)*8 + j  with rg=b>>4,l15=b&15,kcT=k>>5,quad=(k>>3)&3,j=k&7
__device__ __forceinline__ int a32slot(int b, int k) {
  int kcT = k >> 5, quad = (k >> 3) & 3, j = k & 7, rg = b >> 4, l15 = b & 15;
  return ((((kcT * 2 + rg) * 4 + quad) * 16 + l15) * 8) + j;
}

// ---------------- init: h = init_h*m, c = init_c*m ----------------
__global__ void k_init(const float* __restrict__ ih, const float* __restrict__ ic,
                       const int* __restrict__ mask,
                       float* __restrict__ h, float* __restrict__ c) {
  size_t i = (size_t)blockIdx.x * blockDim.x + threadIdx.x;  // over NHe/4
  size_t n = i >> 7;
  float m = (float)mask[n];
  float4 b = ((const float4*)ih)[i];
  float4 d = ((const float4*)ic)[i];
  b.x *= m; b.y *= m; b.z *= m; b.w *= m;
  d.x *= m; d.y *= m; d.z *= m; d.w *= m;
  ((float4*)h)[i] = b; ((float4*)c)[i] = d;
}

// ---------------- mean2 (once): dh16 (frag fp16), dc ----------------
__global__ void k_mean2(const float* __restrict__ x, const float* __restrict__ y,
                        _Float16* __restrict__ dh16, float* __restrict__ oy) {
  int idx = blockIdx.x * blockDim.x + threadIdx.x;
  int b = idx >> 9, k = idx & 511;
  const float* px = x + (size_t)b * Sn * Hn + k;
  const float* py = y + (size_t)b * Sn * Hn + k;
  float sx = 0.f, sy = 0.f;
#pragma unroll 8
  for (int t = 0; t < Sn; ++t) { sx += px[(size_t)t * Hn]; sy += py[(size_t)t * Hn]; }
  oy[idx] = sy * (1.f / Sn);
  dh16[a32slot(b, k)] = (_Float16)(sx * (1.f / Sn));
}

// ---------------- mean over s: two-stage, float4 ----------------
__global__ void k_mean1a(const float* __restrict__ x, float* __restrict__ part) {
  int b = blockIdx.x, sc = blockIdx.y;          // 32 x 8
  int k4 = threadIdx.x & 127;                   // float4 over 512 k
  int so = threadIdx.x >> 7;                    // 0/1
  const float4* px = (const float4*)x + ((size_t)(b * Sn + sc * 64 + so)) * 128 + k4;
  float4 s = make_float4(0.f, 0.f, 0.f, 0.f);
#pragma unroll 4
  for (int t = 0; t < 32; ++t) {
    float4 v = px[(size_t)t * 256];
    s.x += v.x; s.y += v.y; s.z += v.z; s.w += v.w;
  }
  ((float4*)part)[((size_t)(sc * 2 + so) * Bn + b) * 128 + k4] = s;
}
__global__ void k_mean1b(const float* __restrict__ part, _Float16* __restrict__ comb16) {
  int idx = blockIdx.x * blockDim.x + threadIdx.x;   // B*H/4 = 4096
  int b = idx >> 7, k4 = idx & 127;
  float4 s = make_float4(0.f, 0.f, 0.f, 0.f);
#pragma unroll
  for (int p = 0; p < 16; ++p) {
    float4 v = ((const float4*)part)[((size_t)p * Bn + b) * 128 + k4];
    s.x += v.x; s.y += v.y; s.z += v.z; s.w += v.w;
  }
  float vv[4] = {s.x, s.y, s.z, s.w};
#pragma unroll
  for (int jj = 0; jj < 4; ++jj)
    comb16[a32slot(b, k4 * 4 + jj)] = (_Float16)(vv[jj] * (1.f / Sn));
}

// ---------------- small-GEMM weight pre-swizzle (once): gW0..4 + Wd0..7 ----------------
__global__ void k_convS(const float* __restrict__ gW, const float* __restrict__ Wd,
                        _Float16* __restrict__ Shat) {
  int kcT = blockIdx.x, nT4 = blockIdx.y, mat = blockIdx.z;  // 16,4,13
  int tid = threadIdx.x;  // 256
  const float* w = (mat < 5) ? (gW + (size_t)mat * 262144)
                             : (Wd + (size_t)(mat - 5) * 262144);
  size_t sb = ((size_t)((mat * 4 + nT4) * 16 + kcT)) * 4096;
#pragma unroll
  for (int half = 0; half < 2; ++half) {
    int st = half * 256 + tid;             // slot 0..511
    int nj = st >> 6, quad = (st >> 4) & 3, l15 = st & 15;
    int n = nT4 * 128 + nj * 16 + l15;
    int k0 = kcT * 32 + quad * 8;
    f16x8 w8;
#pragma unroll
    for (int j = 0; j < 8; ++j) w8[j] = (_Float16)w[(size_t)(k0 + j) * Hn + n];
    *(f16x8*)&Shat[sb + (size_t)st * 8] = w8;
  }
}

// ---------------- k_small: 13 batched M=32 GEMMs via MFMA (LDS-free) ----------------
__global__ __launch_bounds__(256) void k_small(const _Float16* __restrict__ dh16,
                                               const _Float16* __restrict__ comb16,
                                               const _Float16* __restrict__ Shat,
                                               float* __restrict__ S) {
  const int mat = blockIdx.x, nT4 = blockIdx.y;  // 13, 4
  const int tid = threadIdx.x;
  const int lane = tid & 63, wid = tid >> 6;
  const int quad = lane >> 4, l15 = lane & 15;
  const _Float16* A16 = (mat == 1 || mat == 3) ? comb16 : dh16;
  const _Float16* Sb = Shat + ((size_t)((mat * 4 + nT4) * 16)) * 4096;

  f32x4 acc[2][2];
#pragma unroll
  for (int rg = 0; rg < 2; ++rg)
#pragma unroll
    for (int nj = 0; nj < 2; ++nj) acc[rg][nj] = (f32x4){0.f, 0.f, 0.f, 0.f};

#pragma unroll 4
  for (int kcT = 0; kcT < 16; ++kcT) {
    f16x8 a0 = *(const f16x8*)&A16[(((kcT * 2 + 0) * 4 + quad) * 16 + l15) * 8];
    f16x8 a1 = *(const f16x8*)&A16[(((kcT * 2 + 1) * 4 + quad) * 16 + l15) * 8];
    f16x8 b0 = *(const f16x8*)&Sb[(size_t)kcT * 4096 + (((wid * 2 + 0) * 4 + quad) * 16 + l15) * 8];
    f16x8 b1 = *(const f16x8*)&Sb[(size_t)kcT * 4096 + (((wid * 2 + 1) * 4 + quad) * 16 + l15) * 8];
    acc[0][0] = __builtin_amdgcn_mfma_f32_16x16x32_f16(a0, b0, acc[0][0], 0, 0, 0);
    acc[0][1] = __builtin_amdgcn_mfma_f32_16x16x32_f16(a0, b1, acc[0][1], 0, 0, 0);
    acc[1][0] = __builtin_amdgcn_mfma_f32_16x16x32_f16(a1, b0, acc[1][0], 0, 0, 0);
    acc[1][1] = __builtin_amdgcn_mfma_f32_16x16x32_f16(a1, b1, acc[1][1], 0, 0, 0);
  }
#pragma unroll
  for (int rg = 0; rg < 2; ++rg)
#pragma unroll
    for (int nj = 0; nj < 2; ++nj)
#pragma unroll
      for (int r = 0; r < 4; ++r) {
        int brow = rg * 16 + quad * 4 + r;
        int col = nT4 * 128 + (wid * 2 + nj) * 16 + l15;
        S[(size_t)mat * 16384 + brow * 512 + col] = acc[rg][nj][r];
      }
}

// ---------------- dummy combine: gd/go inline from S, reads gemm1d partials ----------------
__global__ void k_dummy2(const float* __restrict__ pnum, const float* __restrict__ pden,
                         const float* __restrict__ S, const float* __restrict__ gb,
                         const float* __restrict__ dc,
                         _Float16* __restrict__ dh16o, float* __restrict__ dc2) {
  int idx = blockIdx.x * blockDim.x + threadIdx.x;  // B*H
  int b = idx >> 9, k = idx & 511;
  float gd = sigf(S[idx] + S[16384 + idx] + gb[k]);
  float go = sigf(S[2 * 16384 + idx] + S[3 * 16384 + idx] + gb[512 + k]);
  float ed = __expf(gd);
  float num = ed * dc[idx], den = ed;
#pragma unroll
  for (int q = 0; q < 4; ++q) {
    num += pnum[(size_t)(b * 4 + q) * 512 + k];
    den += pden[(size_t)(b * 4 + q) * 512 + k];
  }
  float d = num / den;
  dc2[idx] = d;
  dh16o[a32slot(b, k)] = (_Float16)(go * tanhf(d));
}

// ---------------- weight pre-swizzle: f32 [g][k][n] -> fp16 frag-order superblocks ----------------
// Bhat superblock sb = (t*16 + nT)*16 + kcT, 8192 halfs (16KB) each.
__global__ void k_convw(const float* __restrict__ Wx, const float* __restrict__ Wh,
                        const float* __restrict__ Wsm, const float* __restrict__ Wi,
                        _Float16* __restrict__ Bhat) {
  int kcT = blockIdx.x, nT = blockIdx.y, tg = blockIdx.z;  // 16,16,40
  int t = tg >> 3, g = tg & 7;
  const float* base;
  if (t == 0)      base = Wx  + (size_t)g * 262144;
  else if (t == 1) base = Wh  + (size_t)g * 524288;
  else if (t == 2) base = Wh  + (size_t)g * 524288 + 262144;
  else if (t == 3) base = Wsm + (size_t)g * 262144;
  else             base = Wi  + (size_t)g * 262144;
  size_t sbase = ((size_t)(t * 16 + nT) * 16 + kcT) * 8192 + (size_t)g * 1024;
  int lane = threadIdx.x;  // 64 threads
  for (int cch = lane; cch < 128; cch += 64) {
    int ni = cch >> 6, quad = (cch >> 4) & 3, l15 = cch & 15;
    int n = nT * 32 + ni * 16 + l15;
    int k0 = kcT * 32 + quad * 8;
    f16x8 w8;
#pragma unroll
    for (int j = 0; j < 8; ++j) w8[j] = (_Float16)base[(size_t)(k0 + j) * Hn + n];
    *(f16x8*)&Bhat[sbase + (size_t)cch * 8] = w8;
  }
}

// ---------------- gWhf pre-swizzle (once): superblock (nT4*16+kcT), 4096 halfs ----------------
__global__ void k_convG(const float* __restrict__ gW, _Float16* __restrict__ Ghat) {
  int kcT = blockIdx.x, nT4 = blockIdx.y;  // 16, 4
  int tid = threadIdx.x;                   // 256
  const float* w = gW + (size_t)5 * Hn * Hn;
  size_t sb = ((size_t)(nT4 * 16 + kcT)) * 4096;
#pragma unroll
  for (int half = 0; half < 2; ++half) {
    int st = half * 256 + tid;             // slot 0..511
    int nj = st >> 6, quad = (st >> 4) & 3, l15 = st & 15;
    int n = nT4 * 128 + nj * 16 + l15;
    int k0 = kcT * 32 + quad * 8;
    f16x8 w8;
#pragma unroll
    for (int j = 0; j < 8; ++j) w8[j] = (_Float16)w[(size_t)(k0 + j) * Hn + n];
    *(f16x8*)&Ghat[sb + (size_t)st * 8] = w8;
  }
}

// ---------------- A pre-convert per layer: ALL terms 0..3 in one pass ----------------
__global__ void k_prepAll(const float* __restrict__ h, const int* __restrict__ pos,
                          _Float16* __restrict__ Ahat) {
  const int mb = blockIdx.x, kcT = blockIdx.y;  // 128,16
  const int tid = threadIdx.x;  // 256
#pragma unroll
  for (int half = 0; half < 2; ++half) {
    int st = half * 256 + tid;
    int rg = st >> 6, quad = (st >> 4) & 3, l15 = st & 15;
    int r = mb * 128 + rg * 16 + l15;
    int srow = r & (Sn - 1);
    int k0 = kcT * 32 + quad * 8;
    const float* base = h + (size_t)r * Hn + k0;
    float v0[8], v1[8], v2[8], v3[8];
#pragma unroll
    for (int j = 0; j < 8; ++j) { v0[j] = base[j]; v1[j] = 0.f; v2[j] = 0.f; v3[j] = 0.f; }
    if (srow >= 1) { const float* p = base - Hn;
#pragma unroll
      for (int j = 0; j < 8; ++j) v1[j] += p[j]; }
    if (srow >= 2) { const float* p = base - 2 * Hn;
#pragma unroll
      for (int j = 0; j < 8; ++j) v1[j] += p[j]; }
    if (srow <= Sn - 2) { const float* p = base + Hn;
#pragma unroll
      for (int j = 0; j < 8; ++j) v2[j] += p[j]; }
    if (srow <= Sn - 3) { const float* p = base + 2 * Hn;
#pragma unroll
      for (int j = 0; j < 8; ++j) v2[j] += p[j]; }
    int pp = pos[r];
    if (pp) {
      const float* p = h + ((size_t)((r >> 9) * Sn + pp - 1)) * Hn + k0;
#pragma unroll
      for (int j = 0; j < 8; ++j) v3[j] = p[j];
    }
    size_t stoff = (size_t)st * 8;
    f16x8 o0, o1, o2, o3;
#pragma unroll
    for (int j = 0; j < 8; ++j) {
      o0[j] = (_Float16)v0[j]; o1[j] = (_Float16)v1[j];
      o2[j] = (_Float16)v2[j]; o3[j] = (_Float16)v3[j];
    }
    *(f16x8*)&Ahat[((size_t)(0 * 128 + mb) * 16 + kcT) * 4096 + stoff] = o0;
    *(f16x8*)&Ahat[((size_t)(1 * 128 + mb) * 16 + kcT) * 4096 + stoff] = o1;
    *(f16x8*)&Ahat[((size_t)(2 * 128 + mb) * 16 + kcT) * 4096 + stoff] = o2;
    *(f16x8*)&Ahat[((size_t)(3 * 128 + mb) * 16 + kcT) * 4096 + stoff] = o3;
  }
}

// word term (t=4): layer-invariant, run once
__global__ void k_prepW(const float* __restrict__ w, const int* __restrict__ mask,
                        _Float16* __restrict__ Ahat) {
  const int mb = blockIdx.x, kcT = blockIdx.y;  // 128,16
  const int tid = threadIdx.x;
  size_t sb = ((size_t)(4 * 128 + mb) * 16 + kcT) * 4096;
#pragma unroll
  for (int half = 0; half < 2; ++half) {
    int st = half * 256 + tid;
    int rg = st >> 6, quad = (st >> 4) & 3, l15 = st & 15;
    int r = mb * 128 + rg * 16 + l15;
    int k0 = kcT * 32 + quad * 8;
    float mf = (float)mask[r];
    const float* base = w + (size_t)r * Hn + k0;
    f16x8 o8;
#pragma unroll
    for (int j = 0; j < 8; ++j) o8[j] = (_Float16)(base[j] * mf);
    *(f16x8*)&Ahat[sb + (size_t)st * 8] = o8;
  }
}

// ---------------- G-GEMM fused with dummy-softmax partial reduction ----------------
// gfA computed inline from S4 + gb (k_gates2 eliminated).
__global__ __launch_bounds__(256, 2) void k_gemm1d(const _Float16* __restrict__ Ahat,
                                                   const _Float16* __restrict__ Ghat,
                                                   const float* __restrict__ S,
                                                   const float* __restrict__ gb,
                                                   const float* __restrict__ cbuf,
                                                   const int* __restrict__ mask,
                                                   float* __restrict__ pnum,
                                                   float* __restrict__ pden) {
  __shared__ _Float16 As[2][4096];
  __shared__ _Float16 Bs[2][4096];
  __shared__ float red[4][2][128];
  const int tid = threadIdx.x;
  const int mb = blockIdx.x, nT4 = blockIdx.y;
  const int lane = tid & 63, wid = tid >> 6;
  const int quad = lane >> 4, l15 = lane & 15;
  const int afo0 = (((wid * 2 + 0) * 4 + quad) * 16 + l15) * 8;
  const int afo1 = (((wid * 2 + 1) * 4 + quad) * 16 + l15) * 8;

  f32x4 acc[2][8];
#pragma unroll
  for (int mi = 0; mi < 2; ++mi)
#pragma unroll
    for (int nj = 0; nj < 8; ++nj) acc[mi][nj] = (f32x4){0.f, 0.f, 0.f, 0.f};

  auto stage = [&](int buf, int kcT) {
    const int4* sa = (const int4*)Ahat + ((size_t)(mb * 16 + kcT) << 9);
    const int4* sbp = (const int4*)Ghat + ((size_t)(nT4 * 16 + kcT) << 9);
#pragma unroll
    for (int q = 0; q < 2; ++q) {
      gl_lds16(sa + q * 256 + tid, &As[buf][(q * 256 + tid) * 8]);
      gl_lds16(sbp + q * 256 + tid, &Bs[buf][(q * 256 + tid) * 8]);
    }
  };

  stage(0, 0);
  __syncthreads();
#pragma unroll 1
  for (int kcT = 0; kcT < 16; ++kcT) {
    const int cur = kcT & 1;
    if (kcT < 15) stage(cur ^ 1, kcT + 1);
    f16x8 a0 = *(const f16x8*)&As[cur][afo0];
    f16x8 a1 = *(const f16x8*)&As[cur][afo1];
#pragma unroll
    for (int nj = 0; nj < 8; ++nj) {
      f16x8 bh = *(const f16x8*)&Bs[cur][((nj * 4 + quad) * 16 + l15) * 8];
      acc[0][nj] = __builtin_amdgcn_mfma_f32_16x16x32_f16(a0, bh, acc[0][nj], 0, 0, 0);
      acc[1][nj] = __builtin_amdgcn_mfma_f32_16x16x32_f16(a1, bh, acc[1][nj], 0, 0, 0);
    }
    __syncthreads();
  }

  // ---- fused dummy-softmax partial epilogue ----
  const int bb = mb >> 2;
  float gfa[8], nsum[8], dsum[8];
#pragma unroll
  for (int nj = 0; nj < 8; ++nj) {
    int col = nT4 * 128 + nj * 16 + l15;
    gfa[nj] = S[4 * 16384 + bb * 512 + col] + gb[1024 + col];
    nsum[nj] = 0.f; dsum[nj] = 0.f;
  }
#pragma unroll
  for (int mi = 0; mi < 2; ++mi) {
#pragma unroll
    for (int r = 0; r < 4; ++r) {
      int row = mb * 128 + wid * 32 + mi * 16 + quad * 4 + r;
      float mf = (float)mask[row];
      const float* crow = cbuf + (size_t)row * 512 + nT4 * 128 + l15;
#pragma unroll
      for (int nj = 0; nj < 8; ++nj) {
        float e = __expf(sigf(acc[mi][nj][r] + gfa[nj])) * mf;
        nsum[nj] += e * crow[nj * 16];
        dsum[nj] += e;
      }
    }
  }
#pragma unroll
  for (int nj = 0; nj < 8; ++nj) {
    nsum[nj] += __shfl_xor(nsum[nj], 16);
    nsum[nj] += __shfl_xor(nsum[nj], 32);
    dsum[nj] += __shfl_xor(dsum[nj], 16);
    dsum[nj] += __shfl_xor(dsum[nj], 32);
  }
  if (quad == 0) {
#pragma unroll
    for (int nj = 0; nj < 8; ++nj) {
      red[wid][0][nj * 16 + l15] = nsum[nj];
      red[wid][1][nj * 16 + l15] = dsum[nj];
    }
  }
  __syncthreads();
  {
    int cc = tid & 127, which = tid >> 7;   // 256 threads -> 2 x 128
    float v = red[0][which][cc] + red[1][which][cc] + red[2][which][cc] + red[3][which][cc];
    float* dst = which ? pden : pnum;
    dst[(size_t)mb * 512 + nT4 * 128 + cc] = v;
  }
}

// ---------------- mega GEMM: round-4 proven schedule (two-phase, counted vmcnt) ----------------
// Tile: 256 rows x 32 cols x 8 groups, 512 threads = 8 waves (wave = 64r x 16c x 8g),
// BK=64 (2 kcT chunks), LDS = 2 x (32KB A + 32KB B) = 128KB, 1 block/CU.
__global__ __launch_bounds__(512, 2) void k_mega(
    const float* __restrict__ c,
    const _Float16* __restrict__ Ahat, const _Float16* __restrict__ Bhat,
    const int* __restrict__ pos, const int* __restrict__ mask,
    const float* __restrict__ dc, const float* __restrict__ dWd,
    const float* __restrict__ bias,
    float* __restrict__ hout, float* __restrict__ cout) {
  __shared__ _Float16 As[2][16384];   // [buf][(kk*2+mb2)*4096 + slot*8]
  __shared__ _Float16 Bs[2][16384];   // [buf][kk*8192 + ghalf*4096 + ...]

  const int tid = threadIdx.x;        // 512
  const int id = blockIdx.x;          // 1024
  const int xcd = id & 7;
  const int loc = id >> 3;            // 0..127
  const int mt = xcd * 8 + (loc >> 4);  // 0..63 (per-XCD contiguous M-tiles)
  const int nT = loc & 15;
  const int m0 = mt * 256;
  const int n0 = nT * 32;
  const int bb = m0 >> 9;             // batch index

  const int lane = tid & 63, wid = tid >> 6;
  const int quad = lane >> 4, l15 = lane & 15;
  const int row_grp = wid >> 1;       // 0..3 -> rows [m0+row_grp*64, +64)
  const int col_half = wid & 1;       // 0..1 -> cols [n0+col_half*16, +16)
  const int mb2 = row_grp >> 1;
  const int rg0 = (row_grp & 1) * 4;

  const int afoA0 = (mb2 * 4096) + ((rg0 * 4 + quad) * 16 + l15) * 8;
  const int afoA1 = (2 * 4096 + mb2 * 4096) + ((rg0 * 4 + quad) * 16 + l15) * 8;
  const int bfo = col_half * 512 + quad * 128 + l15 * 8;

  f32x4 acc[8][4];
#pragma unroll
  for (int g = 0; g < 8; ++g)
#pragma unroll
    for (int mi = 0; mi < 4; ++mi) acc[g][mi] = (f32x4){0.f, 0.f, 0.f, 0.f};

  auto stageA = [&](int buf, int kt2) {
    const int t = kt2 >> 3, kc2 = (kt2 & 7) * 2;
#pragma unroll
    for (int kk = 0; kk < 2; ++kk)
#pragma unroll
      for (int m2 = 0; m2 < 2; ++m2) {
        const int4* src = (const int4*)Ahat +
            ((size_t)((t * 128 + mt * 2 + m2) * 16 + kc2 + kk)) * 512;
        gl_lds16(src + tid, &As[buf][(kk * 2 + m2) * 4096 + tid * 8]);
      }
#pragma unroll
    for (int kk = 0; kk < 2; ++kk) {
      const int4* srcb = (const int4*)Bhat +
          ((size_t)((t * 16 + nT) * 16 + kc2 + kk)) * 1024;
      gl_lds16(srcb + tid, &Bs[buf][kk * 8192 + tid * 8]);
    }
  };
  auto stageB = [&](int buf, int kt2) {
    const int t = kt2 >> 3, kc2 = (kt2 & 7) * 2;
#pragma unroll
    for (int kk = 0; kk < 2; ++kk) {
      const int4* srcb = (const int4*)Bhat +
          ((size_t)((t * 16 + nT) * 16 + kc2 + kk)) * 1024 + 512;
      gl_lds16(srcb + tid, &Bs[buf][kk * 8192 + 4096 + tid * 8]);
    }
  };

  stageA(0, 0);
  stageB(0, 0);

#pragma unroll 1
  for (int kt = 0; kt < 40; ++kt) {
    const int cur = kt & 1;
    const int nbuf = cur ^ 1;
    // ---- phase A: g0-3 ----
    VMCNT(2);
    __builtin_amdgcn_s_barrier();
    f16x8 a[4][2], b[4];
#pragma unroll
    for (int mi = 0; mi < 4; ++mi) {
      a[mi][0] = *(const f16x8*)&As[cur][afoA0 + mi * 512];
      a[mi][1] = *(const f16x8*)&As[cur][afoA1 + mi * 512];
    }
#pragma unroll
    for (int g = 0; g < 4; ++g) b[g] = *(const f16x8*)&Bs[cur][g * 1024 + bfo];
    if (kt < 39) stageA(nbuf, kt + 1);
    asm volatile("s_waitcnt lgkmcnt(0)" ::: "memory");
    __builtin_amdgcn_sched_barrier(0);
    __builtin_amdgcn_s_setprio(1);
#pragma unroll
    for (int g = 0; g < 4; ++g) {
#pragma unroll
      for (int mi = 0; mi < 4; ++mi)
        acc[g][mi] = __builtin_amdgcn_mfma_f32_16x16x32_f16(a[mi][0], b[g], acc[g][mi], 0, 0, 0);
    }
    f16x8 b1[4];
#pragma unroll
    for (int g = 0; g < 4; ++g) b1[g] = *(const f16x8*)&Bs[cur][8192 + g * 1024 + bfo];
    asm volatile("s_waitcnt lgkmcnt(0)" ::: "memory");
    __builtin_amdgcn_sched_barrier(0);
#pragma unroll
    for (int g = 0; g < 4; ++g) {
#pragma unroll
      for (int mi = 0; mi < 4; ++mi)
        acc[g][mi] = __builtin_amdgcn_mfma_f32_16x16x32_f16(a[mi][1], b1[g], acc[g][mi], 0, 0, 0);
    }
    __builtin_amdgcn_s_setprio(0);
    // ---- phase B: g4-7 ----
    if (kt < 39) { VMCNT(6); }
    else         { VMCNT(0); }
    __builtin_amdgcn_s_barrier();
    f16x8 c0[4], c1[4];
#pragma unroll
    for (int g = 0; g < 4; ++g) {
      c0[g] = *(const f16x8*)&Bs[cur][4096 + g * 1024 + bfo];
      c1[g] = *(const f16x8*)&Bs[cur][8192 + 4096 + g * 1024 + bfo];
    }
    if (kt < 39) stageB(nbuf, kt + 1);
    asm volatile("s_waitcnt lgkmcnt(0)" ::: "memory");
    __builtin_amdgcn_sched_barrier(0);
    __builtin_amdgcn_s_setprio(1);
#pragma unroll
    for (int g = 0; g < 4; ++g) {
#pragma unroll
      for (int mi = 0; mi < 4; ++mi)
        acc[4 + g][mi] = __builtin_amdgcn_mfma_f32_16x16x32_f16(a[mi][0], c0[g], acc[4 + g][mi], 0, 0, 0);
    }
#pragma unroll
    for (int g = 0; g < 4; ++g) {
#pragma unroll
      for (int mi = 0; mi < 4; ++mi)
        acc[4 + g][mi] = __builtin_amdgcn_mfma_f32_16x16x32_f16(a[mi][1], c1[g], acc[4 + g][mi], 0, 0, 0);
    }
    __builtin_amdgcn_s_setprio(0);
    __builtin_amdgcn_s_barrier();
  }

  // ---- fused epilogue (per thread: 16 rows x 1 col) ----
  const int col = n0 + col_half * 16 + l15;
  const float tdcv = dc[bb * Hn + col];
  float biasr[8], dwdr[8];
#pragma unroll
  for (int g = 0; g < 8; ++g) {
    biasr[g] = bias[g * Hn + col];
    dwdr[g] = dWd[((size_t)g * Bn + bb) * Hn + col];
  }

#pragma unroll
  for (int mi = 0; mi < 4; ++mi) {
#pragma unroll
    for (int r = 0; r < 4; ++r) {
      const int row = m0 + row_grp * 64 + mi * 16 + quad * 4 + r;
      const int srow = row & (Sn - 1);
      const float mf = (float)mask[row];
      const int pp = pos[row];
      const size_t rb = (size_t)row * Hn;
      float cf = c[rb + col];
      float cb = 0.f, ca = 0.f;
      if (srow >= 1) cb = c[rb - Hn + col];
      if (srow >= 2) cb += c[rb - 2 * Hn + col];
      if (srow <= Sn - 2) ca = c[rb + Hn + col];
      if (srow <= Sn - 3) ca += c[rb + 2 * Hn + col];
      float sw = pp ? c[((size_t)(bb * Sn + pp - 1)) * Hn + col] : 0.f;
      float z[8];
#pragma unroll
      for (int g = 0; g < 8; ++g)
        z[g] = acc[g][mi][r] + biasr[g] + dwdr[g];
      float e0 = __expf(sigf(z[0]));
      float e1 = __expf(sigf(z[1]));
      float e2 = __expf(sigf(z[2]));
      float e3 = __expf(sigf(z[3]));
      float e4 = __expf(sigf(z[4]));
      float e5 = __expf(sigf(z[5]));
      float inv = 1.f / (e0 + e1 + e2 + e3 + e4 + e5);
      float o = sigf(z[6]);
      float u = tanhf(z[7]);
      float cn = inv * (e0 * cb + e1 * ca + e2 * cf + e3 * tdcv + e4 * sw + e5 * u);
      cout[rb + col] = cn * mf;
      hout[rb + col] = o * tanhf(cn) * mf;
    }
  }
}

extern "C" void kernel_launch(void* const* d_in, const int* in_sizes, int n_in,
                              void* d_out, int out_size, void* d_ws, size_t ws_size,
                              hipStream_t stream) {
  (void)in_sizes; (void)n_in; (void)out_size; (void)ws_size;
  const float* word   = (const float*)d_in[0];
  const float* init_h = (const float*)d_in[1];
  const float* init_c = (const float*)d_in[2];
  const float* Wx     = (const float*)d_in[3];
  const float* Wh     = (const float*)d_in[4];
  const float* Wi     = (const float*)d_in[5];
  const float* Wdm    = (const float*)d_in[6];
  const float* Wsm    = (const float*)d_in[7];
  const float* bias   = (const float*)d_in[8];
  const float* gW     = (const float*)d_in[9];
  const float* gb     = (const float*)d_in[10];
  const int*   pos    = (const int*)d_in[11];
  const int*   mask   = (const int*)d_in[12];

  float* ws = (float*)d_ws;
  size_t off = 0;
  auto alloc = [&](size_t nel) { float* p = ws + off; off += nel; return p; };
  float* cA   = alloc(NHe);
  float* cB   = alloc(NHe);
  float* hS   = alloc(NHe);
  _Float16* Ahat = (_Float16*)alloc(5 * NHe / 2);           // 84 MB
  _Float16* Bhat = (_Float16*)alloc(5 * 8 * 512 * 512 / 2); // 21 MB
  _Float16* Ghat = (_Float16*)alloc(512 * 512 / 2);         // 0.5 MB
  _Float16* Shat = (_Float16*)alloc(13 * 512 * 512 / 2);    // 6.8 MB
  float* S    = alloc(13 * 16384);                          // 0.85 MB
  float* part = alloc(16 * Bn * Hn);
  float* pnum = alloc(128 * 512);
  float* pden = alloc(128 * 512);
  _Float16* dh16A = (_Float16*)alloc(8192);
  _Float16* dh16B = (_Float16*)alloc(8192);
  _Float16* comb16 = (_Float16*)alloc(8192);
  float* dc   = alloc(Bn * Hn);
  float* dc2  = alloc(Bn * Hn);
  // total ~ 217 MB

  dim3 blk(256);
  int g4 = (int)(NHe / 4 / 256);          // 8192 blocks
  int gbh = (Bn * Hn) / 256;              // 64 blocks

  k_convw<<<dim3(16, 16, 40), dim3(64), 0, stream>>>(Wx, Wh, Wsm, Wi, Bhat);
  k_convG<<<dim3(16, 4), blk, 0, stream>>>(gW, Ghat);
  k_convS<<<dim3(16, 4, 13), blk, 0, stream>>>(gW, Wdm, Shat);
  k_prepW<<<dim3(128, 16), blk, 0, stream>>>(word, mask, Ahat);
  k_init<<<g4, blk, 0, stream>>>(init_h, init_c, mask, hS, cA);
  k_mean2<<<gbh, blk, 0, stream>>>(hS, cA, dh16A, dc);

  float* ccur = cA; float* cnxt = cB;
  _Float16* dhc = dh16A; _Float16* dhn = dh16B;
  for (int l = 0; l < NLAYER; ++l) {
    k_prepAll<<<dim3(128, 16), blk, 0, stream>>>(hS, pos, Ahat);
    k_mean1a<<<dim3(Bn, 8), blk, 0, stream>>>(hS, part);
    k_mean1b<<<16, blk, 0, stream>>>(part, comb16);
    k_small<<<dim3(13, 4), blk, 0, stream>>>(dhc, comb16, Shat, S);
    k_gemm1d<<<dim3(128, 4), blk, 0, stream>>>(Ahat, Ghat, S, gb, ccur, mask, pnum, pden);
    k_dummy2<<<gbh, blk, 0, stream>>>(pnum, pden, S, gb, dc, dhn, dc2);

    float* hout = (l == NLAYER - 1) ? (float*)d_out : hS;
    k_mega<<<dim3(1024), dim3(512), 0, stream>>>(
        ccur, Ahat, Bhat, pos, mask, dc, S + (size_t)5 * 16384, bias, hout, cnxt);

    float* t1;
    t1 = ccur; ccur = cnxt; cnxt = t1;
    t1 = dc; dc = dc2; dc2 = t1;
    _Float16* t2 = dhc; dhc = dhn; dhn = t2;
  }
}